// Round 1
// 812.006 us; speedup vs baseline: 2.2143x; 2.2143x over previous
//
#include <hip/hip_runtime.h>

// Problem constants (from reference): N=10000, D_IN=128, F1=F2=20, D_OUT=128
constexpr int NN   = 10000;
constexpr int DIN  = 128;
constexpr int F    = 20;       // F1 == F2 == 20
constexpr int DOUT = 128;

// adjmm tiling: block = 256 threads = 128 rows x 2 k-phases.
// Each block covers TM rows x KRANGE k's; t-slice for the k-range sits in LDS.
constexpr int KSPLIT = 25;
constexpr int KRANGE = NN / KSPLIT;          // 400
constexpr int TM     = 128;                  // rows per block
constexpr int ROWBLK = (NN + TM - 1) / TM;   // 79
constexpr int NFLT4  = NN * F / 4;           // 50000 float4 in an NxF buffer

// ---------------------------------------------------------------------------
// out[i,f] = sum_k x[i,k] * W[k,f]   (K=128, F=20)  -> t1
// ---------------------------------------------------------------------------
__global__ __launch_bounds__(256) void gemm_x_w1(const float* __restrict__ x,
                                                 const float* __restrict__ W,
                                                 float* __restrict__ out) {
    int t = blockIdx.x * 256 + threadIdx.x;
    if (t >= NN * F) return;
    int i = t / F, f = t % F;
    const float4* xp = (const float4*)(x + (size_t)i * DIN);
    float s = 0.f;
#pragma unroll
    for (int k4 = 0; k4 < DIN / 4; ++k4) {
        float4 xv = xp[k4];
        int k = k4 * 4;
        s += xv.x * W[(k + 0) * F + f];
        s += xv.y * W[(k + 1) * F + f];
        s += xv.z * W[(k + 2) * F + f];
        s += xv.w * W[(k + 3) * F + f];
    }
    out[t] = s;
}

// ---------------------------------------------------------------------------
// out[i,g] = sum_f in[i,f] * W[f,g]   (K=20, F=20)
// ---------------------------------------------------------------------------
__global__ __launch_bounds__(256) void gemm_h_w2(const float* __restrict__ h,
                                                 const float* __restrict__ W,
                                                 float* __restrict__ out) {
    int t = blockIdx.x * 256 + threadIdx.x;
    if (t >= NN * F) return;
    int i = t / F, g = t % F;
    const float* hp = h + (size_t)i * F;
    float s = 0.f;
#pragma unroll
    for (int f = 0; f < F; ++f) s += hp[f] * W[f * F + g];
    out[t] = s;
}

// ---------------------------------------------------------------------------
// bias+relu (atomic-fallback path only)
// ---------------------------------------------------------------------------
__global__ __launch_bounds__(256) void bias_relu(const float* __restrict__ in,
                                                 const float* __restrict__ b,
                                                 float* __restrict__ out) {
    int t = blockIdx.x * 256 + threadIdx.x;
    if (t >= NN * F) return;
    out[t] = fmaxf(in[t] + b[t % F], 0.f);
}

// ---------------------------------------------------------------------------
// adjmm: out_partial[by, i, :F] = adj[i, k-range(by)] @ t[k-range(by), :F]
//
// - t slice (KRANGE x F = 32 KB) staged once into LDS; inner-loop t reads are
//   2-distinct-address LDS broadcasts (banks {0-3} vs {16-19}: conflict-free,
//   each ds_read_b128 serves both k-phases).
// - adj streamed straight from global: lane pair (2r, 2r+1) handles row r,
//   phases interleave k in float4 granules -> each wave-inst touches
//   32 rows x 32 B contiguous = 16-line-equivalent ideal coalescing.
// - One barrier per block, no SMEM in the hot loop, no per-tile vmcnt drains.
// - PART=1: store per-ksplit partials (no atomic RMW). PART=0: atomicAdd
//   (workspace-too-small fallback).
// - REV=1: run k-loop + block mapping in reverse so this dispatch starts on
//   the adj tail the previous dispatch left in the 256 MB Infinity Cache.
// ---------------------------------------------------------------------------
template <int REV, int PART>
__global__ __launch_bounds__(256) void adjmm(const float* __restrict__ adj,
                                             const float* __restrict__ t,
                                             float* __restrict__ out) {
    __shared__ __align__(16) float tl[KRANGE * F];   // 32000 B

    const int tid = threadIdx.x;
    const int bx = REV ? ((int)gridDim.x - 1 - (int)blockIdx.x) : (int)blockIdx.x;
    const int by = REV ? ((int)gridDim.y - 1 - (int)blockIdx.y) : (int)blockIdx.y;
    const int row0 = bx * TM;
    const int k0   = by * KRANGE;

    // stage t[k0 .. k0+KRANGE)[0..F) -> LDS : 2000 float4, contiguous
    {
        const float4* src = (const float4*)(t + (size_t)k0 * F);
        float4* dst = (float4*)tl;
#pragma unroll
        for (int i = 0; i < 8; ++i) {
            int idx = tid + i * 256;
            if (idx < KRANGE * F / 4) dst[idx] = src[idx];
        }
    }
    __syncthreads();

    const int r   = tid >> 1;        // 0..127 : row within block
    const int p   = tid & 1;         // k-phase
    const int row = row0 + r;
    if (row < NN) {
        float4 acc[5];
#pragma unroll
        for (int c = 0; c < 5; ++c) acc[c] = make_float4(0.f, 0.f, 0.f, 0.f);

        const float4* ap = (const float4*)(adj + (size_t)row * NN + k0);
#pragma unroll 2
        for (int m = 0; m < KRANGE / 8; ++m) {
            const int mm = REV ? (KRANGE / 8 - 1 - m) : m;
            float4 a = ap[2 * mm + p];                 // adj[row, k0+8mm+4p ..+3]
            const float* trow = tl + (8 * mm + 4 * p) * F;
#pragma unroll
            for (int j = 0; j < 4; ++j) {
                const float aj = (j == 0) ? a.x : (j == 1) ? a.y : (j == 2) ? a.z : a.w;
                const float4* tp = (const float4*)(trow + j * F);
#pragma unroll
                for (int c = 0; c < 5; ++c) {
                    float4 tv = tp[c];
                    acc[c].x += aj * tv.x;
                    acc[c].y += aj * tv.y;
                    acc[c].z += aj * tv.z;
                    acc[c].w += aj * tv.w;
                }
            }
        }

        // combine the two phase lanes (partner lane always active: same row)
#pragma unroll
        for (int c = 0; c < 5; ++c) {
            acc[c].x += __shfl_xor(acc[c].x, 1);
            acc[c].y += __shfl_xor(acc[c].y, 1);
            acc[c].z += __shfl_xor(acc[c].z, 1);
            acc[c].w += __shfl_xor(acc[c].w, 1);
        }

        if (PART) {
            if (p == 0) {
                float4* op = (float4*)(out + ((size_t)by * NN + row) * F);
#pragma unroll
                for (int c = 0; c < 5; ++c) op[c] = acc[c];
            }
        } else {
            if (p == 0) {
                float* op = out + (size_t)row * F;
#pragma unroll
                for (int c = 0; c < 5; ++c) {
                    atomicAdd(op + c * 4 + 0, acc[c].x);
                    atomicAdd(op + c * 4 + 1, acc[c].y);
                    atomicAdd(op + c * 4 + 2, acc[c].z);
                    atomicAdd(op + c * 4 + 3, acc[c].w);
                }
            }
        }
    }
}

// ---------------------------------------------------------------------------
// reduce the KSPLIT partial buffers; optionally fuse bias+relu.
// ---------------------------------------------------------------------------
template <int BIASRELU>
__global__ __launch_bounds__(256) void reduce_p(const float* __restrict__ P,
                                                const float* __restrict__ b,
                                                float* __restrict__ out) {
    int t = blockIdx.x * 256 + threadIdx.x;
    if (t >= NFLT4) return;
    float4 s = ((const float4*)P)[t];
    for (int k = 1; k < KSPLIT; ++k) {
        float4 v = ((const float4*)P)[(size_t)k * NFLT4 + t];
        s.x += v.x; s.y += v.y; s.z += v.z; s.w += v.w;
    }
    if (BIASRELU) {
        int f4 = t % (F / 4);
        float4 bv = ((const float4*)b)[f4];
        s.x = fmaxf(s.x + bv.x, 0.f);
        s.y = fmaxf(s.y + bv.y, 0.f);
        s.z = fmaxf(s.z + bv.z, 0.f);
        s.w = fmaxf(s.w + bv.w, 0.f);
    }
    ((float4*)out)[t] = s;
}

// ---------------------------------------------------------------------------
// out[i,f] = relu( relu( sum_g u[i,g]*W3[g,f] + b3[f] ) + x[i,f] )
// ---------------------------------------------------------------------------
__global__ __launch_bounds__(256) void final_fuse(const float* __restrict__ u,
                                                  const float* __restrict__ W3,
                                                  const float* __restrict__ b3,
                                                  const float* __restrict__ x,
                                                  float* __restrict__ out) {
    int t = blockIdx.x * 256 + threadIdx.x;
    if (t >= NN * DOUT) return;
    int i = t / DOUT, f = t % DOUT;
    const float* up = u + (size_t)i * F;
    float s = b3[f];
#pragma unroll
    for (int g = 0; g < F; ++g) s += up[g] * W3[g * DOUT + f];
    float h = fmaxf(s, 0.f);
    out[t] = fmaxf(h + x[t], 0.f);
}

// ---------------------------------------------------------------------------
extern "C" void kernel_launch(void* const* d_in, const int* in_sizes, int n_in,
                              void* d_out, int out_size, void* d_ws, size_t ws_size,
                              hipStream_t stream) {
    const float* x   = (const float*)d_in[0];
    const float* adj = (const float*)d_in[1];
    const float* W1  = (const float*)d_in[2];
    const float* b1  = (const float*)d_in[3];
    const float* W2  = (const float*)d_in[4];
    const float* b2  = (const float*)d_in[5];
    const float* W3  = (const float*)d_in[6];
    const float* b3  = (const float*)d_in[7];
    float* out = (float*)d_out;

    float* A = (float*)d_ws;            // N x F
    float* C = A + (size_t)NN * F;      // N x F
    float* P = C + (size_t)NN * F;      // KSPLIT x N x F partials (20 MB)
    const size_t nf_bytes = (size_t)NN * F * sizeof(float);
    const size_t need = nf_bytes * (2 + KSPLIT);

    const int blk_nf  = (NN * F + 255) / 256;        // 782
    const int blk_nf4 = (NFLT4 + 255) / 256;         // 196
    const int blk_no  = (NN * DOUT + 255) / 256;     // 5000
    dim3 agrid(ROWBLK, KSPLIT);                      // 79 x 25 = 1975 blocks

    if (ws_size >= need) {
        // Layer 1: h1 = relu(adj @ (x@W1) + b1)
        gemm_x_w1<<<blk_nf, 256, 0, stream>>>(x, W1, A);
        adjmm<0, 1><<<agrid, 256, 0, stream>>>(adj, A, P);
        reduce_p<1><<<blk_nf4, 256, 0, stream>>>(P, b1, C);

        // Layer 2: h2 = relu(adj @ (h1@W2) + b2)   (adj streamed in reverse)
        gemm_h_w2<<<blk_nf, 256, 0, stream>>>(C, W2, A);
        adjmm<1, 1><<<agrid, 256, 0, stream>>>(adj, A, P);
        reduce_p<1><<<blk_nf4, 256, 0, stream>>>(P, b2, C);

        // Layer 3 (reassociated): u = adj @ h2 ; out = relu(relu(u@W3+b3)+x)
        adjmm<0, 1><<<agrid, 256, 0, stream>>>(adj, C, P);
        reduce_p<0><<<blk_nf4, 256, 0, stream>>>(P, nullptr, A);
        final_fuse<<<blk_no, 256, 0, stream>>>(A, W3, b3, x, out);
    } else {
        // Fallback: atomic accumulation (3 NxF buffers only)
        float* B = P;  // only NxF of it used
        gemm_x_w1<<<blk_nf, 256, 0, stream>>>(x, W1, A);
        hipMemsetAsync(B, 0, nf_bytes, stream);
        adjmm<0, 0><<<agrid, 256, 0, stream>>>(adj, A, B);
        bias_relu<<<blk_nf, 256, 0, stream>>>(B, b1, C);

        gemm_h_w2<<<blk_nf, 256, 0, stream>>>(C, W2, A);
        hipMemsetAsync(B, 0, nf_bytes, stream);
        adjmm<1, 0><<<agrid, 256, 0, stream>>>(adj, A, B);
        bias_relu<<<blk_nf, 256, 0, stream>>>(B, b2, C);

        hipMemsetAsync(A, 0, nf_bytes, stream);
        adjmm<0, 0><<<agrid, 256, 0, stream>>>(adj, C, A);
        final_fuse<<<blk_no, 256, 0, stream>>>(A, W3, b3, x, out);
    }
}